// Round 1
// baseline (1098.992 us; speedup 1.0000x reference)
//
#include <hip/hip_runtime.h>
#include <float.h>

#define DECAY 0.99f
#define EPS 1e-5f
#define NROWS 65536
#define DIM 256
#define NEMB 1024

// ---------- K0a: ||e_k||^2 per code + zero counts ----------
__global__ __launch_bounds__(256) void k_enorm(const float* __restrict__ embed,
                                               float* __restrict__ enorm2,
                                               int* __restrict__ counts) {
    int kk = threadIdx.x & 63;
    int dg = threadIdx.x >> 6;              // 0..3
    int k  = blockIdx.x * 64 + kk;          // 16 blocks * 64 = 1024 codes
    float s = 0.f;
    for (int d = dg; d < DIM; d += 4) {
        float v = embed[(size_t)d * NEMB + k];
        s = fmaf(v, v, s);
    }
    __shared__ float red[4][64];
    red[dg][kk] = s;
    __syncthreads();
    if (dg == 0) enorm2[k] = red[0][kk] + red[1][kk] + red[2][kk] + red[3][kk];
    int gt = blockIdx.x * 256 + threadIdx.x;
    if (gt < NEMB) counts[gt] = 0;
}

// ---------- K0b: transpose embed [256][1024] -> embedT [1024][256] ----------
__global__ __launch_bounds__(256) void k_transpose(const float* __restrict__ embed,
                                                   float* __restrict__ embedT) {
    __shared__ float tile[32][33];
    int k0 = blockIdx.x * 32, d0 = blockIdx.y * 32;
    int tx = threadIdx.x, ty = threadIdx.y;  // 32 x 8
#pragma unroll
    for (int i = 0; i < 4; i++)
        tile[ty + 8 * i][tx] = embed[(size_t)(d0 + ty + 8 * i) * NEMB + k0 + tx];
    __syncthreads();
#pragma unroll
    for (int i = 0; i < 4; i++)
        embedT[(size_t)(k0 + ty + 8 * i) * DIM + d0 + tx] = tile[tx][ty + 8 * i];
}

// ---------- K1: fused GEMM-argmin. block = 128 rows x all 1024 codes ----------
__global__ __launch_bounds__(256) void k_argmin(const float* __restrict__ input,
                                                const float* __restrict__ embed,
                                                const float* __restrict__ enorm2,
                                                int* __restrict__ ind,
                                                float* __restrict__ out_ind) {
    __shared__ float As[32][132];   // [d][row], padded
    __shared__ float Bs[32][132];   // [d][code], padded
    __shared__ float Es[128];
    const int tid = threadIdx.x;
    const int tr = tid >> 4;        // 0..15 -> rows tr*8..+7
    const int tc = tid & 15;        // 0..15 -> codes tc*8..+7 (within tile)
    const int rb = blockIdx.x * 128;

    float bv[8];
    int   bi[8];
#pragma unroll
    for (int r = 0; r < 8; r++) { bv[r] = FLT_MAX; bi[r] = 0x7fffffff; }

    for (int ct = 0; ct < 8; ct++) {
        const int cb = ct * 128;
        float acc[8][8];
#pragma unroll
        for (int r = 0; r < 8; r++)
#pragma unroll
            for (int c = 0; c < 8; c++) acc[r][c] = 0.f;

        for (int dc = 0; dc < 8; dc++) {
            // stage A: 128 rows x 32 d (transpose to d-major)
#pragma unroll
            for (int j = 0; j < 4; j++) {
                int f = tid + 256 * j;
                int row = f >> 3, dq = f & 7;
                const float4 v = *reinterpret_cast<const float4*>(
                    input + (size_t)(rb + row) * DIM + dc * 32 + dq * 4);
                As[dq * 4 + 0][row] = v.x;
                As[dq * 4 + 1][row] = v.y;
                As[dq * 4 + 2][row] = v.z;
                As[dq * 4 + 3][row] = v.w;
            }
            // stage B: 32 d x 128 codes (already d-major in memory)
#pragma unroll
            for (int j = 0; j < 4; j++) {
                int f = tid + 256 * j;
                int d = f >> 5, cq = f & 31;
                const float4 v = *reinterpret_cast<const float4*>(
                    embed + (size_t)(dc * 32 + d) * NEMB + cb + cq * 4);
                *reinterpret_cast<float4*>(&Bs[d][cq * 4]) = v;
            }
            if (dc == 0 && tid < 128) Es[tid] = enorm2[cb + tid];
            __syncthreads();

#pragma unroll 8
            for (int d = 0; d < 32; d++) {
                float a[8], b[8];
                *reinterpret_cast<float4*>(&a[0]) = *reinterpret_cast<float4*>(&As[d][tr * 8]);
                *reinterpret_cast<float4*>(&a[4]) = *reinterpret_cast<float4*>(&As[d][tr * 8 + 4]);
                *reinterpret_cast<float4*>(&b[0]) = *reinterpret_cast<float4*>(&Bs[d][tc * 8]);
                *reinterpret_cast<float4*>(&b[4]) = *reinterpret_cast<float4*>(&Bs[d][tc * 8 + 4]);
#pragma unroll
                for (int r = 0; r < 8; r++)
#pragma unroll
                    for (int c = 0; c < 8; c++) acc[r][c] = fmaf(a[r], b[c], acc[r][c]);
            }
            __syncthreads();
        }
        // running argmin update (score = ||e||^2 - 2*dot; ||x||^2 is row-const)
#pragma unroll
        for (int c = 0; c < 8; c++) {
            float e = Es[tc * 8 + c];
            int cid = cb + tc * 8 + c;
#pragma unroll
            for (int r = 0; r < 8; r++) {
                float s = fmaf(-2.f, acc[r][c], e);
                if (s < bv[r]) { bv[r] = s; bi[r] = cid; }
            }
        }
        __syncthreads();  // protect Es/As/Bs before next tile's staging
    }

    // cross-thread reduce over the 16 code-threads per row (reuse As/Bs as scratch)
    float* redv = &As[0][0];
    int*   redi = reinterpret_cast<int*>(&Bs[0][0]);
#pragma unroll
    for (int r = 0; r < 8; r++) {
        redv[(tr * 8 + r) * 17 + tc] = bv[r];
        redi[(tr * 8 + r) * 17 + tc] = bi[r];
    }
    __syncthreads();
    if (tid < 128) {
        float best = FLT_MAX; int bidx = 0x7fffffff;
        for (int t = 0; t < 16; t++) {
            float v = redv[tid * 17 + t];
            int   i = redi[tid * 17 + t];
            if (v < best || (v == best && i < bidx)) { best = v; bidx = i; }
        }
        ind[rb + tid] = bidx;
        out_ind[rb + tid] = (float)bidx;   // argmin index as float output
    }
}

// ---------- K2: quantize_st output + per-block diff partials ----------
__global__ __launch_bounds__(256) void k_quant(const float* __restrict__ input,
                                               const float* __restrict__ embedT,
                                               const int* __restrict__ ind,
                                               float* __restrict__ out_q,
                                               float* __restrict__ partials) {
    const int tid = threadIdx.x;
    const unsigned gid = blockIdx.x * 256 + tid;
    float s = 0.f;
#pragma unroll
    for (int j = 0; j < 8; j++) {
        size_t i4 = (size_t)gid + (size_t)j * 524288u;   // 4194304 float4 total
        int row = (int)(i4 >> 6);
        int d4  = (int)(i4 & 63);
        float4 iv = *reinterpret_cast<const float4*>(input + i4 * 4);
        int k = ind[row];
        float4 qv = *reinterpret_cast<const float4*>(embedT + (size_t)k * DIM + d4 * 4);
        float dx = qv.x - iv.x, dy = qv.y - iv.y, dz = qv.z - iv.z, dw = qv.w - iv.w;
        float4 ov;
        ov.x = iv.x + dx; ov.y = iv.y + dy; ov.z = iv.z + dz; ov.w = iv.w + dw;
        *reinterpret_cast<float4*>(out_q + i4 * 4) = ov;
        s += dx * dx + dy * dy + dz * dz + dw * dw;
    }
    __shared__ float red[256];
    red[tid] = s;
    __syncthreads();
    for (int off = 128; off > 0; off >>= 1) {
        if (tid < off) red[tid] += red[tid + off];
        __syncthreads();
    }
    if (tid == 0) partials[blockIdx.x] = red[0];
}

// ---------- K2b: finalize diff ----------
__global__ __launch_bounds__(256) void k_diff(const float* __restrict__ partials,
                                              float* __restrict__ out_diff) {
    __shared__ float red[256];
    int tid = threadIdx.x;
    float s = 0.f;
    for (int j = 0; j < 8; j++) s += partials[tid * 8 + j];
    red[tid] = s;
    __syncthreads();
    for (int off = 128; off > 0; off >>= 1) {
        if (tid < off) red[tid] += red[tid + off];
        __syncthreads();
    }
    if (tid == 0) out_diff[0] = red[0] / 16777216.0f;
}

// ---------- K3: histogram of assignments ----------
__global__ __launch_bounds__(256) void k_hist(const int* __restrict__ ind,
                                              int* __restrict__ counts) {
    __shared__ int h[NEMB];
    int tid = threadIdx.x;
    for (int j = tid; j < NEMB; j += 256) h[j] = 0;
    __syncthreads();
    for (int i = blockIdx.x * 256 + tid; i < NROWS; i += 64 * 256)
        atomicAdd(&h[ind[i]], 1);
    __syncthreads();
    for (int j = tid; j < NEMB; j += 256)
        if (h[j]) atomicAdd(&counts[j], h[j]);
}

// ---------- K4: scan counts -> offsets/cursor; new_cluster_size, n, cs ----------
__global__ __launch_bounds__(1024) void k_scan(const int* __restrict__ counts,
                                               const float* __restrict__ cluster_size,
                                               int* __restrict__ offsets,
                                               int* __restrict__ cursor,
                                               float* __restrict__ out_ncs,
                                               float* __restrict__ cs) {
    __shared__ int sh[NEMB];
    __shared__ float shf[NEMB];
    int tid = threadIdx.x;
    int c = counts[tid];
    sh[tid] = c;
    __syncthreads();
    for (int off = 1; off < NEMB; off <<= 1) {
        int t = (tid >= off) ? sh[tid - off] : 0;
        __syncthreads();
        sh[tid] += t;
        __syncthreads();
    }
    int excl = sh[tid] - c;
    offsets[tid] = excl;
    cursor[tid]  = excl;
    float ncs = cluster_size[tid] * DECAY + (1.f - DECAY) * (float)c;
    out_ncs[tid] = ncs;
    shf[tid] = ncs;
    __syncthreads();
    for (int off = 512; off > 0; off >>= 1) {
        if (tid < off) shf[tid] += shf[tid + off];
        __syncthreads();
    }
    float n = shf[0];
    cs[tid] = (ncs + EPS) / (n + NEMB * EPS) * n;
}

// ---------- K5: scatter rows by cluster ----------
__global__ __launch_bounds__(256) void k_scatter(const int* __restrict__ ind,
                                                 int* __restrict__ cursor,
                                                 int* __restrict__ sorted) {
    int i = blockIdx.x * 256 + threadIdx.x;
    int k = ind[i];
    int pos = atomicAdd(&cursor[k], 1);
    sorted[pos] = i;
}

// ---------- K6: per-cluster sum + EMA + new_embed ----------
__global__ __launch_bounds__(256) void k_cluster_sum(const float* __restrict__ input,
                                                     const float* __restrict__ embed_avg,
                                                     const int* __restrict__ sorted,
                                                     const int* __restrict__ counts,
                                                     const int* __restrict__ offsets,
                                                     const float* __restrict__ cs,
                                                     float* __restrict__ out_navg,
                                                     float* __restrict__ out_nembed) {
    int k = blockIdx.x;
    int d = threadIdx.x;          // 256 dims
    int cnt = counts[k], base = offsets[k];
    float s = 0.f;
    for (int i = 0; i < cnt; i++) {
        int row = sorted[base + i];
        s += input[(size_t)row * DIM + d];
    }
    float navg = embed_avg[(size_t)d * NEMB + k] * (DECAY * DECAY) + (1.f - DECAY) * s;
    out_navg[(size_t)d * NEMB + k] = navg;
    out_nembed[(size_t)d * NEMB + k] = navg / cs[k];
}

extern "C" void kernel_launch(void* const* d_in, const int* in_sizes, int n_in,
                              void* d_out, int out_size, void* d_ws, size_t ws_size,
                              hipStream_t stream) {
    const float* input        = (const float*)d_in[0];
    const float* embed        = (const float*)d_in[1];
    const float* cluster_size = (const float*)d_in[2];
    const float* embed_avg    = (const float*)d_in[3];

    float* out        = (float*)d_out;
    float* out_q      = out;                       // 16777216
    float* out_diff   = out + 16777216;            // 1
    float* out_ind    = out + 16777217;            // 65536
    float* out_ncs    = out + 16842753;            // 1024
    float* out_navg   = out + 16843777;            // 262144
    float* out_nembed = out + 17105921;            // 262144

    char* ws = (char*)d_ws;
    size_t o = 0;
    int*   w_ind      = (int*)(ws + o);  o += (size_t)NROWS * 4;
    float* w_embedT   = (float*)(ws + o); o += (size_t)DIM * NEMB * 4;
    float* w_enorm    = (float*)(ws + o); o += NEMB * 4;
    int*   w_counts   = (int*)(ws + o);  o += NEMB * 4;
    int*   w_offsets  = (int*)(ws + o);  o += NEMB * 4;
    int*   w_cursor   = (int*)(ws + o);  o += NEMB * 4;
    float* w_cs       = (float*)(ws + o); o += NEMB * 4;
    float* w_partials = (float*)(ws + o); o += 2048 * 4;
    int*   w_sorted   = (int*)(ws + o);  o += (size_t)NROWS * 4;

    k_enorm<<<16, 256, 0, stream>>>(embed, w_enorm, w_counts);
    k_transpose<<<dim3(32, 8), dim3(32, 8), 0, stream>>>(embed, w_embedT);
    k_argmin<<<NROWS / 128, 256, 0, stream>>>(input, embed, w_enorm, w_ind, out_ind);
    k_quant<<<2048, 256, 0, stream>>>(input, w_embedT, w_ind, out_q, w_partials);
    k_diff<<<1, 256, 0, stream>>>(w_partials, out_diff);
    k_hist<<<64, 256, 0, stream>>>(w_ind, w_counts);
    k_scan<<<1, 1024, 0, stream>>>(w_counts, cluster_size, w_offsets, w_cursor, out_ncs, w_cs);
    k_scatter<<<NROWS / 256, 256, 0, stream>>>(w_ind, w_cursor, w_sorted);
    k_cluster_sum<<<NEMB, 256, 0, stream>>>(input, embed_avg, w_sorted, w_counts,
                                            w_offsets, w_cs, out_navg, out_nembed);
}

// Round 2
// 565.780 us; speedup vs baseline: 1.9424x; 1.9424x over previous
//
#include <hip/hip_runtime.h>
#include <float.h>

#define DECAY 0.99f
#define EPS 1e-5f
#define NROWS 65536
#define DIM 256
#define NEMB 1024
#define CH 64            // rows per sub-chunk in segmented reduction
#define MAXSUB 2048      // NROWS/CH + NEMB upper bound on total sub-chunks

// ---------- K0a: ||e_k||^2 per code + zero counts ----------
__global__ __launch_bounds__(256) void k_enorm(const float* __restrict__ embed,
                                               float* __restrict__ enorm2,
                                               int* __restrict__ counts) {
    int kk = threadIdx.x & 63;
    int dg = threadIdx.x >> 6;              // 0..3
    int k  = blockIdx.x * 64 + kk;          // 16 blocks * 64 = 1024 codes
    float s = 0.f;
    for (int d = dg; d < DIM; d += 4) {
        float v = embed[(size_t)d * NEMB + k];
        s = fmaf(v, v, s);
    }
    __shared__ float red[4][64];
    red[dg][kk] = s;
    __syncthreads();
    if (dg == 0) enorm2[k] = red[0][kk] + red[1][kk] + red[2][kk] + red[3][kk];
    int gt = blockIdx.x * 256 + threadIdx.x;
    if (gt < NEMB) counts[gt] = 0;
}

// ---------- K0b: transpose embed [256][1024] -> embedT [1024][256] ----------
__global__ __launch_bounds__(256) void k_transpose(const float* __restrict__ embed,
                                                   float* __restrict__ embedT) {
    __shared__ float tile[32][33];
    int k0 = blockIdx.x * 32, d0 = blockIdx.y * 32;
    int tx = threadIdx.x, ty = threadIdx.y;  // 32 x 8
#pragma unroll
    for (int i = 0; i < 4; i++)
        tile[ty + 8 * i][tx] = embed[(size_t)(d0 + ty + 8 * i) * NEMB + k0 + tx];
    __syncthreads();
#pragma unroll
    for (int i = 0; i < 4; i++)
        embedT[(size_t)(k0 + ty + 8 * i) * DIM + d0 + tx] = tile[tx][ty + 8 * i];
}

// ---------- K1: fused GEMM-argmin. block = 128 rows x all 1024 codes ----------
__global__ __launch_bounds__(256) void k_argmin(const float* __restrict__ input,
                                                const float* __restrict__ embed,
                                                const float* __restrict__ enorm2,
                                                int* __restrict__ ind,
                                                float* __restrict__ out_ind) {
    __shared__ float As[32][132];   // [d][row], padded
    __shared__ float Bs[32][132];   // [d][code], padded
    __shared__ float Es[128];
    const int tid = threadIdx.x;
    const int tr = tid >> 4;        // 0..15 -> rows tr*8..+7
    const int tc = tid & 15;        // 0..15 -> codes tc*8..+7 (within tile)
    const int rb = blockIdx.x * 128;

    float bv[8];
    int   bi[8];
#pragma unroll
    for (int r = 0; r < 8; r++) { bv[r] = FLT_MAX; bi[r] = 0x7fffffff; }

    for (int ct = 0; ct < 8; ct++) {
        const int cb = ct * 128;
        float acc[8][8];
#pragma unroll
        for (int r = 0; r < 8; r++)
#pragma unroll
            for (int c = 0; c < 8; c++) acc[r][c] = 0.f;

        for (int dc = 0; dc < 8; dc++) {
            // stage A: 128 rows x 32 d (transpose to d-major)
#pragma unroll
            for (int j = 0; j < 4; j++) {
                int f = tid + 256 * j;
                int row = f >> 3, dq = f & 7;
                const float4 v = *reinterpret_cast<const float4*>(
                    input + (size_t)(rb + row) * DIM + dc * 32 + dq * 4);
                As[dq * 4 + 0][row] = v.x;
                As[dq * 4 + 1][row] = v.y;
                As[dq * 4 + 2][row] = v.z;
                As[dq * 4 + 3][row] = v.w;
            }
            // stage B: 32 d x 128 codes (already d-major in memory)
#pragma unroll
            for (int j = 0; j < 4; j++) {
                int f = tid + 256 * j;
                int d = f >> 5, cq = f & 31;
                const float4 v = *reinterpret_cast<const float4*>(
                    embed + (size_t)(dc * 32 + d) * NEMB + cb + cq * 4);
                *reinterpret_cast<float4*>(&Bs[d][cq * 4]) = v;
            }
            if (dc == 0 && tid < 128) Es[tid] = enorm2[cb + tid];
            __syncthreads();

#pragma unroll 8
            for (int d = 0; d < 32; d++) {
                float a[8], b[8];
                *reinterpret_cast<float4*>(&a[0]) = *reinterpret_cast<float4*>(&As[d][tr * 8]);
                *reinterpret_cast<float4*>(&a[4]) = *reinterpret_cast<float4*>(&As[d][tr * 8 + 4]);
                *reinterpret_cast<float4*>(&b[0]) = *reinterpret_cast<float4*>(&Bs[d][tc * 8]);
                *reinterpret_cast<float4*>(&b[4]) = *reinterpret_cast<float4*>(&Bs[d][tc * 8 + 4]);
#pragma unroll
                for (int r = 0; r < 8; r++)
#pragma unroll
                    for (int c = 0; c < 8; c++) acc[r][c] = fmaf(a[r], b[c], acc[r][c]);
            }
            __syncthreads();
        }
        // running argmin update (score = ||e||^2 - 2*dot; ||x||^2 is row-const)
#pragma unroll
        for (int c = 0; c < 8; c++) {
            float e = Es[tc * 8 + c];
            int cid = cb + tc * 8 + c;
#pragma unroll
            for (int r = 0; r < 8; r++) {
                float s = fmaf(-2.f, acc[r][c], e);
                if (s < bv[r]) { bv[r] = s; bi[r] = cid; }
            }
        }
        __syncthreads();  // protect Es/As/Bs before next tile's staging
    }

    // cross-thread reduce over the 16 code-threads per row (reuse As/Bs as scratch)
    float* redv = &As[0][0];
    int*   redi = reinterpret_cast<int*>(&Bs[0][0]);
#pragma unroll
    for (int r = 0; r < 8; r++) {
        redv[(tr * 8 + r) * 17 + tc] = bv[r];
        redi[(tr * 8 + r) * 17 + tc] = bi[r];
    }
    __syncthreads();
    if (tid < 128) {
        float best = FLT_MAX; int bidx = 0x7fffffff;
        for (int t = 0; t < 16; t++) {
            float v = redv[tid * 17 + t];
            int   i = redi[tid * 17 + t];
            if (v < best || (v == best && i < bidx)) { best = v; bidx = i; }
        }
        ind[rb + tid] = bidx;
        out_ind[rb + tid] = (float)bidx;   // argmin index as float output
    }
}

// ---------- K2: quantize_st output + per-block diff partials ----------
__global__ __launch_bounds__(256) void k_quant(const float* __restrict__ input,
                                               const float* __restrict__ embedT,
                                               const int* __restrict__ ind,
                                               float* __restrict__ out_q,
                                               float* __restrict__ partials) {
    const int tid = threadIdx.x;
    const unsigned gid = blockIdx.x * 256 + tid;
    float s = 0.f;
#pragma unroll
    for (int j = 0; j < 8; j++) {
        size_t i4 = (size_t)gid + (size_t)j * 524288u;   // 4194304 float4 total
        int row = (int)(i4 >> 6);
        int d4  = (int)(i4 & 63);
        float4 iv = *reinterpret_cast<const float4*>(input + i4 * 4);
        int k = ind[row];
        float4 qv = *reinterpret_cast<const float4*>(embedT + (size_t)k * DIM + d4 * 4);
        float dx = qv.x - iv.x, dy = qv.y - iv.y, dz = qv.z - iv.z, dw = qv.w - iv.w;
        float4 ov;
        ov.x = iv.x + dx; ov.y = iv.y + dy; ov.z = iv.z + dz; ov.w = iv.w + dw;
        *reinterpret_cast<float4*>(out_q + i4 * 4) = ov;
        s += dx * dx + dy * dy + dz * dz + dw * dw;
    }
    __shared__ float red[256];
    red[tid] = s;
    __syncthreads();
    for (int off = 128; off > 0; off >>= 1) {
        if (tid < off) red[tid] += red[tid + off];
        __syncthreads();
    }
    if (tid == 0) partials[blockIdx.x] = red[0];
}

// ---------- K2b: finalize diff ----------
__global__ __launch_bounds__(256) void k_diff(const float* __restrict__ partials,
                                              float* __restrict__ out_diff) {
    __shared__ float red[256];
    int tid = threadIdx.x;
    float s = 0.f;
    for (int j = 0; j < 8; j++) s += partials[tid * 8 + j];
    red[tid] = s;
    __syncthreads();
    for (int off = 128; off > 0; off >>= 1) {
        if (tid < off) red[tid] += red[tid + off];
        __syncthreads();
    }
    if (tid == 0) out_diff[0] = red[0] / 16777216.0f;
}

// ---------- K3: histogram of assignments ----------
__global__ __launch_bounds__(256) void k_hist(const int* __restrict__ ind,
                                              int* __restrict__ counts) {
    __shared__ int h[NEMB];
    int tid = threadIdx.x;
    for (int j = tid; j < NEMB; j += 256) h[j] = 0;
    __syncthreads();
    for (int i = blockIdx.x * 256 + tid; i < NROWS; i += 64 * 256)
        atomicAdd(&h[ind[i]], 1);
    __syncthreads();
    for (int j = tid; j < NEMB; j += 256)
        if (h[j]) atomicAdd(&counts[j], h[j]);
}

// ---------- K4: scans (row offsets + sub-chunk offsets); ncs, n, cs ----------
__global__ __launch_bounds__(1024) void k_scan(const int* __restrict__ counts,
                                               const float* __restrict__ cluster_size,
                                               int* __restrict__ offsets,
                                               int* __restrict__ cursor,
                                               int* __restrict__ substart,
                                               float* __restrict__ out_ncs,
                                               float* __restrict__ cs) {
    __shared__ int sh[NEMB];
    __shared__ float shf[NEMB];
    int tid = threadIdx.x;
    int c = counts[tid];
    // scan #1: row counts -> row offsets
    sh[tid] = c;
    __syncthreads();
    for (int off = 1; off < NEMB; off <<= 1) {
        int t = (tid >= off) ? sh[tid - off] : 0;
        __syncthreads();
        sh[tid] += t;
        __syncthreads();
    }
    int excl = sh[tid] - c;
    offsets[tid] = excl;
    cursor[tid]  = excl;
    // scan #2: sub-chunk counts (ceil(c/CH)) -> substart
    int sc = (c + CH - 1) / CH;
    __syncthreads();
    sh[tid] = sc;
    __syncthreads();
    for (int off = 1; off < NEMB; off <<= 1) {
        int t = (tid >= off) ? sh[tid - off] : 0;
        __syncthreads();
        sh[tid] += t;
        __syncthreads();
    }
    substart[tid] = sh[tid] - sc;
    if (tid == NEMB - 1) substart[NEMB] = sh[tid];
    // EMA cluster size + normalization
    float ncs = cluster_size[tid] * DECAY + (1.f - DECAY) * (float)c;
    out_ncs[tid] = ncs;
    shf[tid] = ncs;
    __syncthreads();
    for (int off = 512; off > 0; off >>= 1) {
        if (tid < off) shf[tid] += shf[tid + off];
        __syncthreads();
    }
    float n = shf[0];
    cs[tid] = (ncs + EPS) / (n + NEMB * EPS) * n;
}

// ---------- K5: scatter rows by cluster ----------
__global__ __launch_bounds__(256) void k_scatter(const int* __restrict__ ind,
                                                 int* __restrict__ cursor,
                                                 int* __restrict__ sorted) {
    int i = blockIdx.x * 256 + threadIdx.x;
    int k = ind[i];
    int pos = atomicAdd(&cursor[k], 1);
    sorted[pos] = i;
}

// ---------- K6a: balanced partial sums. block = one 64-row sub-chunk ----------
__global__ __launch_bounds__(256) void k_psum(const float* __restrict__ input,
                                              const int* __restrict__ sorted,
                                              const int* __restrict__ counts,
                                              const int* __restrict__ offsets,
                                              const int* __restrict__ substart,
                                              float* __restrict__ partial) {
    const int b = blockIdx.x;
    if (b >= substart[NEMB]) return;
    // binary search: largest k with substart[k] <= b
    int lo = 0, hi = NEMB;
    while (hi - lo > 1) {
        int mid = (lo + hi) >> 1;
        if (substart[mid] <= b) lo = mid; else hi = mid;
    }
    const int k     = lo;
    const int chunk = b - substart[k];
    const int cnt   = counts[k];
    const int base  = offsets[k] + chunk * CH;
    const int lim   = min(CH, cnt - chunk * CH);
    const int d     = threadIdx.x;
    float s = 0.f;
    for (int i = 0; i < lim; i++) {
        int row = sorted[base + i];
        s += input[(size_t)row * DIM + d];
    }
    partial[(size_t)b * DIM + d] = s;
}

// ---------- K6b: per-cluster combine (fixed order) + EMA + new_embed ----------
__global__ __launch_bounds__(256) void k_ema(const float* __restrict__ partial,
                                             const float* __restrict__ embed_avg,
                                             const int* __restrict__ substart,
                                             const float* __restrict__ cs,
                                             float* __restrict__ out_navg,
                                             float* __restrict__ out_nembed) {
    const int d = blockIdx.x;           // 256 blocks, one dim each
    const int t = threadIdx.x;
#pragma unroll
    for (int i = 0; i < 4; i++) {
        int k = t + 256 * i;            // coalesced across threads
        int s0 = substart[k], s1 = substart[k + 1];
        float s = 0.f;
        for (int sub = s0; sub < s1; sub++)   // deterministic fixed order
            s += partial[(size_t)sub * DIM + d];
        float navg = embed_avg[(size_t)d * NEMB + k] * (DECAY * DECAY) + (1.f - DECAY) * s;
        out_navg[(size_t)d * NEMB + k] = navg;
        out_nembed[(size_t)d * NEMB + k] = navg / cs[k];
    }
}

extern "C" void kernel_launch(void* const* d_in, const int* in_sizes, int n_in,
                              void* d_out, int out_size, void* d_ws, size_t ws_size,
                              hipStream_t stream) {
    const float* input        = (const float*)d_in[0];
    const float* embed        = (const float*)d_in[1];
    const float* cluster_size = (const float*)d_in[2];
    const float* embed_avg    = (const float*)d_in[3];

    float* out        = (float*)d_out;
    float* out_q      = out;                       // 16777216
    float* out_diff   = out + 16777216;            // 1
    float* out_ind    = out + 16777217;            // 65536
    float* out_ncs    = out + 16842753;            // 1024
    float* out_navg   = out + 16843777;            // 262144
    float* out_nembed = out + 17105921;            // 262144

    char* ws = (char*)d_ws;
    size_t o = 0;
    int*   w_ind      = (int*)(ws + o);   o += (size_t)NROWS * 4;
    float* w_embedT   = (float*)(ws + o); o += (size_t)DIM * NEMB * 4;
    float* w_enorm    = (float*)(ws + o); o += NEMB * 4;
    int*   w_counts   = (int*)(ws + o);   o += NEMB * 4;
    int*   w_offsets  = (int*)(ws + o);   o += NEMB * 4;
    int*   w_cursor   = (int*)(ws + o);   o += NEMB * 4;
    float* w_cs       = (float*)(ws + o); o += NEMB * 4;
    float* w_partials = (float*)(ws + o); o += 2048 * 4;
    int*   w_sorted   = (int*)(ws + o);   o += (size_t)NROWS * 4;
    int*   w_substart = (int*)(ws + o);   o += (NEMB + 4) * 4;
    float* w_partial  = (float*)(ws + o); o += (size_t)MAXSUB * DIM * 4;

    k_enorm<<<16, 256, 0, stream>>>(embed, w_enorm, w_counts);
    k_transpose<<<dim3(32, 8), dim3(32, 8), 0, stream>>>(embed, w_embedT);
    k_argmin<<<NROWS / 128, 256, 0, stream>>>(input, embed, w_enorm, w_ind, out_ind);
    k_quant<<<2048, 256, 0, stream>>>(input, w_embedT, w_ind, out_q, w_partials);
    k_diff<<<1, 256, 0, stream>>>(w_partials, out_diff);
    k_hist<<<64, 256, 0, stream>>>(w_ind, w_counts);
    k_scan<<<1, 1024, 0, stream>>>(w_counts, cluster_size, w_offsets, w_cursor,
                                   w_substart, out_ncs, w_cs);
    k_scatter<<<NROWS / 256, 256, 0, stream>>>(w_ind, w_cursor, w_sorted);
    k_psum<<<MAXSUB, 256, 0, stream>>>(input, w_sorted, w_counts, w_offsets,
                                       w_substart, w_partial);
    k_ema<<<DIM, 256, 0, stream>>>(w_partial, embed_avg, w_substart, w_cs,
                                   out_navg, out_nembed);
}

// Round 3
// 411.516 us; speedup vs baseline: 2.6706x; 1.3749x over previous
//
#include <hip/hip_runtime.h>
#include <float.h>

#define DECAY 0.99f
#define EPS 1e-5f
#define NROWS 65536
#define DIM 256
#define NEMB 1024
#define CH 64            // rows per sub-chunk in segmented reduction
#define MAXSUB 2048      // NROWS/CH + NEMB upper bound on total sub-chunks

typedef _Float16 f16;
typedef _Float16 half8 __attribute__((ext_vector_type(8)));
typedef float f32x4 __attribute__((ext_vector_type(4)));

// ---------- K0a: ||e_k||^2 per code + zero counts ----------
__global__ __launch_bounds__(256) void k_enorm(const float* __restrict__ embed,
                                               float* __restrict__ enorm2,
                                               int* __restrict__ counts) {
    int kk = threadIdx.x & 63;
    int dg = threadIdx.x >> 6;              // 0..3
    int k  = blockIdx.x * 64 + kk;          // 16 blocks * 64 = 1024 codes
    float s = 0.f;
    for (int d = dg; d < DIM; d += 4) {
        float v = embed[(size_t)d * NEMB + k];
        s = fmaf(v, v, s);
    }
    __shared__ float red[4][64];
    red[dg][kk] = s;
    __syncthreads();
    if (dg == 0) enorm2[k] = red[0][kk] + red[1][kk] + red[2][kk] + red[3][kk];
    int gt = blockIdx.x * 256 + threadIdx.x;
    if (gt < NEMB) counts[gt] = 0;
}

// ---------- K0b: transpose embed [256][1024] -> embedT [1024][256] (for k_quant) ----------
__global__ __launch_bounds__(256) void k_transpose(const float* __restrict__ embed,
                                                   float* __restrict__ embedT) {
    __shared__ float tile[32][33];
    int k0 = blockIdx.x * 32, d0 = blockIdx.y * 32;
    int tx = threadIdx.x, ty = threadIdx.y;  // 32 x 8
#pragma unroll
    for (int i = 0; i < 4; i++)
        tile[ty + 8 * i][tx] = embed[(size_t)(d0 + ty + 8 * i) * NEMB + k0 + tx];
    __syncthreads();
#pragma unroll
    for (int i = 0; i < 4; i++)
        embedT[(size_t)(k0 + ty + 8 * i) * DIM + d0 + tx] = tile[tx][ty + 8 * i];
}

// ---------- K0c: embed fp32 [256][1024] -> ehlT f16 [1024][512] ([c][0:256]=hi, [c][256:512]=lo) ----------
__global__ __launch_bounds__(256) void k_esplit(const float* __restrict__ embed,
                                                f16* __restrict__ ehlT) {
    __shared__ float tile[32][33];           // [d-local][c-local]
    int c0 = blockIdx.x * 32, d0 = blockIdx.y * 32;
    int tx = threadIdx.x, ty = threadIdx.y;  // 32 x 8
#pragma unroll
    for (int i = 0; i < 4; i++)
        tile[ty + 8 * i][tx] = embed[(size_t)(d0 + ty + 8 * i) * NEMB + c0 + tx];
    __syncthreads();
#pragma unroll
    for (int i = 0; i < 4; i++) {
        int c = c0 + ty + 8 * i;
        int d = d0 + tx;
        float v = tile[tx][ty + 8 * i];
        f16 h = (f16)v;
        f16 l = (f16)(v - (float)h);
        ehlT[(size_t)c * 512 + d]       = h;
        ehlT[(size_t)c * 512 + 256 + d] = l;
    }
}

// ---------- K1: MFMA GEMM-argmin, f16 hi/lo split (K=768), block = 128 rows x 1024 codes ----------
#define LDS_A  0        // 16KB [128 rows][64 k] f16, XOR-swizzled
#define LDS_B  16384    // 16KB [128 cols][64 k] f16, XOR-swizzled
#define LDS_E  32768    // 4KB  e2[1024] f32
#define LDS_PV 36864    // 1KB  [128][2] float
#define LDS_PI 37888    // 1KB  [128][2] int
#define LDS_SZ 38912

__global__ __launch_bounds__(256) void k_argmin_mfma(const float* __restrict__ input,
                                                     const f16* __restrict__ ehlT,
                                                     const float* __restrict__ enorm2,
                                                     int* __restrict__ ind,
                                                     float* __restrict__ out_ind) {
    __shared__ char lds[LDS_SZ];
    float* Es = (float*)(lds + LDS_E);
    const int tid  = threadIdx.x;
    const int lane = tid & 63;
    const int w    = tid >> 6;        // wave 0..3
    const int wr   = w >> 1;          // row half
    const int wc   = w & 1;           // col half
    const int rb   = blockIdx.x * 128;
    const int l15  = lane & 15;
    const int lkh  = lane >> 4;       // 0..3

    for (int j = tid; j < NEMB; j += 256) Es[j] = enorm2[j];

    float bv[16];
    int   bi[16];
#pragma unroll
    for (int q = 0; q < 16; q++) { bv[q] = FLT_MAX; bi[q] = 0x7fffffff; }

    for (int ct = 0; ct < 8; ct++) {
        const int cb = ct * 128;
        f32x4 acc[4][4];
#pragma unroll
        for (int fr = 0; fr < 4; fr++)
#pragma unroll
            for (int fc = 0; fc < 4; fc++) acc[fr][fc] = (f32x4){0.f, 0.f, 0.f, 0.f};

        for (int kt = 0; kt < 12; kt++) {
            // K segments: kt0-3 xh*eh, kt4-7 xl*eh, kt8-11 xh*el
            const int  ad0  = (kt & 3) * 64;                         // input d offset
            const int  bOff = ((kt >= 8) ? 256 : 0) + (kt & 3) * 64; // ehlT k offset
            const bool alo  = (kt >= 4 && kt < 8);

            __syncthreads();   // previous tile's reads done
            // ---- stage A: 128 rows x 64 k f16 (on-the-fly hi/lo from fp32) ----
#pragma unroll
            for (int j = 0; j < 4; j++) {
                int u = tid + 256 * j;      // 0..1023 granules of 8 f16
                int row = u >> 3, k8 = u & 7;
                const float4* s = (const float4*)(input + (size_t)(rb + row) * DIM + ad0 + k8 * 8);
                float4 v0 = s[0], v1 = s[1];
                half8 h;
                if (!alo) {
                    h[0] = (f16)v0.x; h[1] = (f16)v0.y; h[2] = (f16)v0.z; h[3] = (f16)v0.w;
                    h[4] = (f16)v1.x; h[5] = (f16)v1.y; h[6] = (f16)v1.z; h[7] = (f16)v1.w;
                } else {
                    f16 t;
                    t = (f16)v0.x; h[0] = (f16)(v0.x - (float)t);
                    t = (f16)v0.y; h[1] = (f16)(v0.y - (float)t);
                    t = (f16)v0.z; h[2] = (f16)(v0.z - (float)t);
                    t = (f16)v0.w; h[3] = (f16)(v0.w - (float)t);
                    t = (f16)v1.x; h[4] = (f16)(v1.x - (float)t);
                    t = (f16)v1.y; h[5] = (f16)(v1.y - (float)t);
                    t = (f16)v1.z; h[6] = (f16)(v1.z - (float)t);
                    t = (f16)v1.w; h[7] = (f16)(v1.w - (float)t);
                }
                *(half8*)(lds + LDS_A + row * 128 + ((k8 * 16) ^ ((row & 7) << 4))) = h;
            }
            // ---- stage B: 128 cols x 64 k f16 (direct from ehlT) ----
#pragma unroll
            for (int j = 0; j < 4; j++) {
                int u = tid + 256 * j;
                int col = u >> 3, k8 = u & 7;
                half8 h = *(const half8*)(ehlT + (size_t)(cb + col) * 512 + bOff + k8 * 8);
                *(half8*)(lds + LDS_B + col * 128 + ((k8 * 16) ^ ((col & 7) << 4))) = h;
            }
            __syncthreads();

            // ---- MFMA: 2 ksteps x 4x4 fragments ----
#pragma unroll
            for (int kk = 0; kk < 2; kk++) {
                half8 af[4], bf[4];
                const int kb = kk * 64 + lkh * 16;
#pragma unroll
                for (int f = 0; f < 4; f++) {
                    int ar = wr * 64 + f * 16 + l15;
                    af[f] = *(const half8*)(lds + LDS_A + ar * 128 + (kb ^ ((ar & 7) << 4)));
                    int bc = wc * 64 + f * 16 + l15;
                    bf[f] = *(const half8*)(lds + LDS_B + bc * 128 + (kb ^ ((bc & 7) << 4)));
                }
#pragma unroll
                for (int fr = 0; fr < 4; fr++)
#pragma unroll
                    for (int fc = 0; fc < 4; fc++)
                        acc[fr][fc] = __builtin_amdgcn_mfma_f32_16x16x32_f16(
                            af[fr], bf[fc], acc[fr][fc], 0, 0, 0);
            }
        }

        // ---- epilogue: running per-row argmin over this 128-col slab ----
#pragma unroll
        for (int fc = 0; fc < 4; fc++) {
            int col = cb + wc * 64 + fc * 16 + l15;
            float e2 = Es[col];
#pragma unroll
            for (int fr = 0; fr < 4; fr++)
#pragma unroll
                for (int r = 0; r < 4; r++) {
                    float s = fmaf(-2.f, acc[fr][fc][r], e2);
                    int q = fr * 4 + r;
                    if (s < bv[q]) { bv[q] = s; bi[q] = col; }
                }
        }
    }

    // ---- cross-lane reduce: min over the 16 col-lanes in each row group ----
#pragma unroll
    for (int q = 0; q < 16; q++) {
        float v = bv[q]; int i = bi[q];
#pragma unroll
        for (int m = 1; m <= 8; m <<= 1) {
            float ov = __shfl_xor(v, m, 64);
            int   oi = __shfl_xor(i, m, 64);
            if (ov < v || (ov == v && oi < i)) { v = ov; i = oi; }
        }
        bv[q] = v; bi[q] = i;
    }
    float* PV = (float*)(lds + LDS_PV);
    int*   PI = (int*)(lds + LDS_PI);
    if (l15 == 0) {
#pragma unroll
        for (int fr = 0; fr < 4; fr++)
#pragma unroll
            for (int r = 0; r < 4; r++) {
                int rrow = wr * 64 + fr * 16 + lkh * 4 + r;
                PV[rrow * 2 + wc] = bv[fr * 4 + r];
                PI[rrow * 2 + wc] = bi[fr * 4 + r];
            }
    }
    __syncthreads();
    if (tid < 128) {
        float v0 = PV[tid * 2], v1 = PV[tid * 2 + 1];
        int   i0 = PI[tid * 2], i1 = PI[tid * 2 + 1];
        int best;
        if (v1 < v0) best = i1;
        else if (v0 < v1) best = i0;
        else best = min(i0, i1);
        ind[rb + tid] = best;
        out_ind[rb + tid] = (float)best;
    }
}

// ---------- K2: quantize_st output + per-block diff partials ----------
__global__ __launch_bounds__(256) void k_quant(const float* __restrict__ input,
                                               const float* __restrict__ embedT,
                                               const int* __restrict__ ind,
                                               float* __restrict__ out_q,
                                               float* __restrict__ partials) {
    const int tid = threadIdx.x;
    const unsigned gid = blockIdx.x * 256 + tid;
    float s = 0.f;
#pragma unroll
    for (int j = 0; j < 8; j++) {
        size_t i4 = (size_t)gid + (size_t)j * 524288u;   // 4194304 float4 total
        int row = (int)(i4 >> 6);
        int d4  = (int)(i4 & 63);
        float4 iv = *reinterpret_cast<const float4*>(input + i4 * 4);
        int k = ind[row];
        float4 qv = *reinterpret_cast<const float4*>(embedT + (size_t)k * DIM + d4 * 4);
        float dx = qv.x - iv.x, dy = qv.y - iv.y, dz = qv.z - iv.z, dw = qv.w - iv.w;
        float4 ov;
        ov.x = iv.x + dx; ov.y = iv.y + dy; ov.z = iv.z + dz; ov.w = iv.w + dw;
        *reinterpret_cast<float4*>(out_q + i4 * 4) = ov;
        s += dx * dx + dy * dy + dz * dz + dw * dw;
    }
    __shared__ float red[256];
    red[tid] = s;
    __syncthreads();
    for (int off = 128; off > 0; off >>= 1) {
        if (tid < off) red[tid] += red[tid + off];
        __syncthreads();
    }
    if (tid == 0) partials[blockIdx.x] = red[0];
}

// ---------- K2b: finalize diff ----------
__global__ __launch_bounds__(256) void k_diff(const float* __restrict__ partials,
                                              float* __restrict__ out_diff) {
    __shared__ float red[256];
    int tid = threadIdx.x;
    float s = 0.f;
    for (int j = 0; j < 8; j++) s += partials[tid * 8 + j];
    red[tid] = s;
    __syncthreads();
    for (int off = 128; off > 0; off >>= 1) {
        if (tid < off) red[tid] += red[tid + off];
        __syncthreads();
    }
    if (tid == 0) out_diff[0] = red[0] / 16777216.0f;
}

// ---------- K3: histogram of assignments ----------
__global__ __launch_bounds__(256) void k_hist(const int* __restrict__ ind,
                                              int* __restrict__ counts) {
    __shared__ int h[NEMB];
    int tid = threadIdx.x;
    for (int j = tid; j < NEMB; j += 256) h[j] = 0;
    __syncthreads();
    for (int i = blockIdx.x * 256 + tid; i < NROWS; i += 64 * 256)
        atomicAdd(&h[ind[i]], 1);
    __syncthreads();
    for (int j = tid; j < NEMB; j += 256)
        if (h[j]) atomicAdd(&counts[j], h[j]);
}

// ---------- K4: scans (row offsets + sub-chunk offsets); ncs, n, cs ----------
__global__ __launch_bounds__(1024) void k_scan(const int* __restrict__ counts,
                                               const float* __restrict__ cluster_size,
                                               int* __restrict__ offsets,
                                               int* __restrict__ cursor,
                                               int* __restrict__ substart,
                                               float* __restrict__ out_ncs,
                                               float* __restrict__ cs) {
    __shared__ int sh[NEMB];
    __shared__ float shf[NEMB];
    int tid = threadIdx.x;
    int c = counts[tid];
    sh[tid] = c;
    __syncthreads();
    for (int off = 1; off < NEMB; off <<= 1) {
        int t = (tid >= off) ? sh[tid - off] : 0;
        __syncthreads();
        sh[tid] += t;
        __syncthreads();
    }
    int excl = sh[tid] - c;
    offsets[tid] = excl;
    cursor[tid]  = excl;
    int sc = (c + CH - 1) / CH;
    __syncthreads();
    sh[tid] = sc;
    __syncthreads();
    for (int off = 1; off < NEMB; off <<= 1) {
        int t = (tid >= off) ? sh[tid - off] : 0;
        __syncthreads();
        sh[tid] += t;
        __syncthreads();
    }
    substart[tid] = sh[tid] - sc;
    if (tid == NEMB - 1) substart[NEMB] = sh[tid];
    float ncs = cluster_size[tid] * DECAY + (1.f - DECAY) * (float)c;
    out_ncs[tid] = ncs;
    shf[tid] = ncs;
    __syncthreads();
    for (int off = 512; off > 0; off >>= 1) {
        if (tid < off) shf[tid] += shf[tid + off];
        __syncthreads();
    }
    float n = shf[0];
    cs[tid] = (ncs + EPS) / (n + NEMB * EPS) * n;
}

// ---------- K5: scatter rows by cluster ----------
__global__ __launch_bounds__(256) void k_scatter(const int* __restrict__ ind,
                                                 int* __restrict__ cursor,
                                                 int* __restrict__ sorted) {
    int i = blockIdx.x * 256 + threadIdx.x;
    int k = ind[i];
    int pos = atomicAdd(&cursor[k], 1);
    sorted[pos] = i;
}

// ---------- K6a: balanced partial sums. block = one 64-row sub-chunk ----------
__global__ __launch_bounds__(256) void k_psum(const float* __restrict__ input,
                                              const int* __restrict__ sorted,
                                              const int* __restrict__ counts,
                                              const int* __restrict__ offsets,
                                              const int* __restrict__ substart,
                                              float* __restrict__ partial) {
    const int b = blockIdx.x;
    if (b >= substart[NEMB]) return;
    int lo = 0, hi = NEMB;
    while (hi - lo > 1) {
        int mid = (lo + hi) >> 1;
        if (substart[mid] <= b) lo = mid; else hi = mid;
    }
    const int k     = lo;
    const int chunk = b - substart[k];
    const int cnt   = counts[k];
    const int base  = offsets[k] + chunk * CH;
    const int lim   = min(CH, cnt - chunk * CH);
    const int d     = threadIdx.x;
    float s = 0.f;
    for (int i = 0; i < lim; i++) {
        int row = sorted[base + i];
        s += input[(size_t)row * DIM + d];
    }
    partial[(size_t)b * DIM + d] = s;
}

// ---------- K6b: per-cluster combine (fixed order) + EMA + new_embed ----------
__global__ __launch_bounds__(256) void k_ema(const float* __restrict__ partial,
                                             const float* __restrict__ embed_avg,
                                             const int* __restrict__ substart,
                                             const float* __restrict__ cs,
                                             float* __restrict__ out_navg,
                                             float* __restrict__ out_nembed) {
    const int d = blockIdx.x;
    const int t = threadIdx.x;
#pragma unroll
    for (int i = 0; i < 4; i++) {
        int k = t + 256 * i;
        int s0 = substart[k], s1 = substart[k + 1];
        float s = 0.f;
        for (int sub = s0; sub < s1; sub++)
            s += partial[(size_t)sub * DIM + d];
        float navg = embed_avg[(size_t)d * NEMB + k] * (DECAY * DECAY) + (1.f - DECAY) * s;
        out_navg[(size_t)d * NEMB + k] = navg;
        out_nembed[(size_t)d * NEMB + k] = navg / cs[k];
    }
}

extern "C" void kernel_launch(void* const* d_in, const int* in_sizes, int n_in,
                              void* d_out, int out_size, void* d_ws, size_t ws_size,
                              hipStream_t stream) {
    const float* input        = (const float*)d_in[0];
    const float* embed        = (const float*)d_in[1];
    const float* cluster_size = (const float*)d_in[2];
    const float* embed_avg    = (const float*)d_in[3];

    float* out        = (float*)d_out;
    float* out_q      = out;                       // 16777216
    float* out_diff   = out + 16777216;            // 1
    float* out_ind    = out + 16777217;            // 65536
    float* out_ncs    = out + 16842753;            // 1024
    float* out_navg   = out + 16843777;            // 262144
    float* out_nembed = out + 17105921;            // 262144

    char* ws = (char*)d_ws;
    size_t o = 0;
    int*   w_ind      = (int*)(ws + o);   o += (size_t)NROWS * 4;
    float* w_embedT   = (float*)(ws + o); o += (size_t)DIM * NEMB * 4;
    float* w_enorm    = (float*)(ws + o); o += NEMB * 4;
    int*   w_counts   = (int*)(ws + o);   o += NEMB * 4;
    int*   w_offsets  = (int*)(ws + o);   o += NEMB * 4;
    int*   w_cursor   = (int*)(ws + o);   o += NEMB * 4;
    float* w_cs       = (float*)(ws + o); o += NEMB * 4;
    float* w_partials = (float*)(ws + o); o += 2048 * 4;
    int*   w_sorted   = (int*)(ws + o);   o += (size_t)NROWS * 4;
    int*   w_substart = (int*)(ws + o);   o += (NEMB + 4) * 4;
    float* w_partial  = (float*)(ws + o); o += (size_t)MAXSUB * DIM * 4;
    f16*   w_ehlT     = (f16*)(ws + o);   o += (size_t)NEMB * 512 * 2;

    k_enorm<<<16, 256, 0, stream>>>(embed, w_enorm, w_counts);
    k_transpose<<<dim3(32, 8), dim3(32, 8), 0, stream>>>(embed, w_embedT);
    k_esplit<<<dim3(32, 8), dim3(32, 8), 0, stream>>>(embed, w_ehlT);
    k_argmin_mfma<<<NROWS / 128, 256, 0, stream>>>(input, w_ehlT, w_enorm, w_ind, out_ind);
    k_quant<<<2048, 256, 0, stream>>>(input, w_embedT, w_ind, out_q, w_partials);
    k_diff<<<1, 256, 0, stream>>>(w_partials, out_diff);
    k_hist<<<64, 256, 0, stream>>>(w_ind, w_counts);
    k_scan<<<1, 1024, 0, stream>>>(w_counts, cluster_size, w_offsets, w_cursor,
                                   w_substart, out_ncs, w_cs);
    k_scatter<<<NROWS / 256, 256, 0, stream>>>(w_ind, w_cursor, w_sorted);
    k_psum<<<MAXSUB, 256, 0, stream>>>(input, w_sorted, w_counts, w_offsets,
                                       w_substart, w_partial);
    k_ema<<<DIM, 256, 0, stream>>>(w_partial, embed_avg, w_substart, w_cs,
                                   out_navg, out_nembed);
}